// Round 7
// baseline (435.960 us; speedup 1.0000x reference)
//
#include <hip/hip_runtime.h>
#include <hip/hip_cooperative_groups.h>

// Multi-scale parabolic morphological closing.
// Algebra: dilations along different axes commute (max-plus), as do erosions:
//   closing = ev.eh.dv.dh = (eh.ev).(dh.dv)
//   phase DIL: ws  = dh(dv(x))      (both max)
//   phase ERO: out = eh(ev(ws))     (both min)
// weight(d) = c * (4/W^2) * d^2 — pow2 * small-int products are exact.
//
// R11 (from R10 post-mortem): I$-thrash falsified (scale-clustering neutral);
// ledger = fill(47, harness tax) + dil(37) + ero(37); per-kernel VALU-busy
// ~21us, residual stall unidentified AND k_vh counters have been invisible
// since R6 (five 47us harness fills own the top-5 table). This round:
// COOPERATIVE SINGLE-DISPATCH MERGE — k_closing = dil ; grid.sync() ; ero.
//  - 2048 blocks x 256thr at 8 blocks/CU (LDS 18.7KB, VGPR 32) = exactly
//    co-residency capacity; hipLaunchCooperativeKernel checked, fallback to
//    the proven 2-dispatch path on any error.
//  - merged ~72us dispatch > 47us fills -> counters visible next round.
//  - removes one dispatch ramp + gap + drain (~4-8us predicted).
// Inner math byte-identical to R9/R10 -> absmax stays 0.0.

namespace cg = cooperative_groups;

#define HH 256
#define WW 256
#define BC 32
#define NS 4
#define HW (HH * WW)
#define SLICE ((long)BC * HW)

// LDS row stride per scale: 2W + 256 + 4 (multiple of 4 floats -> 16B rows)
template <int W> struct LdsStride { static constexpr int v = 2 * W + 256 + 4; };
// double buffer sized for the largest NT>1 scale (W=16: 292); W=32 (324) is
// single-tile and uses the buffer un-doubled.
#define LBUF_FLOATS (2 * 8 * 292)

// ---- horizontal pass over one padded LDS row; thread computes 8 outputs ----
template <int W, bool IS_MAX>
__device__ __forceinline__ void hpass_lds(const float* __restrict__ lw, float cw,
                                          float acc[8])
{
    const float PAD = IS_MAX ? -1e30f : 1e30f;
#pragma unroll
    for (int pp = 0; pp < 8; ++pp) acc[pp] = PAD;
#pragma unroll
    for (int u = 0; u < (8 + 2 * W) / 4; ++u) {
        const float4 vv = *(const float4*)(lw + 4 * u);
        const float vs[4] = {vv.x, vv.y, vv.z, vv.w};
#pragma unroll
        for (int pp = 0; pp < 8; ++pp) {
#pragma unroll
            for (int e = 0; e < 4; e += 2) {            // paired -> v_max3
                const int d1 = 4 * u + e - W - pp;      // compile-time
                const int d2 = d1 + 1;
                const bool ok1 = (d1 >= -W) && (d1 <= W);
                const bool ok2 = (d2 >= -W) && (d2 <= W);
                const float K1 = (float)(d1 * d1);
                const float K2 = (float)(d2 * d2);
                if (ok1 && ok2) {
                    const float c1 = IS_MAX ? fmaf(cw, -K1, vs[e])
                                            : fmaf(cw,  K1, vs[e]);
                    const float c2 = IS_MAX ? fmaf(cw, -K2, vs[e + 1])
                                            : fmaf(cw,  K2, vs[e + 1]);
                    acc[pp] = IS_MAX ? fmaxf(acc[pp], fmaxf(c1, c2))
                                     : fminf(acc[pp], fminf(c1, c2));
                } else if (ok1) {
                    const float c1 = IS_MAX ? fmaf(cw, -K1, vs[e])
                                            : fmaf(cw,  K1, vs[e]);
                    acc[pp] = IS_MAX ? fmaxf(acc[pp], c1) : fminf(acc[pp], c1);
                } else if (ok2) {
                    const float c2 = IS_MAX ? fmaf(cw, -K2, vs[e + 1])
                                            : fmaf(cw,  K2, vs[e + 1]);
                    acc[pp] = IS_MAX ? fmaxf(acc[pp], c2) : fminf(acc[pp], c2);
                }
            }
        }
    }
}

// ---- vertical pass; thread = one column, 8 consecutive output rows ----
template <int W, bool IS_MAX, bool CLAMP>
__device__ __forceinline__ void vpass_core(const float* __restrict__ img, int x,
                                           int h0, float cw, float acc[8])
{
    const float PAD = IS_MAX ? -1e30f : 1e30f;
    constexpr int TOT = 8 + 2 * W;
#pragma unroll
    for (int pp = 0; pp < 8; ++pp) acc[pp] = PAD;
#pragma unroll
    for (int ch = 0; ch < TOT / 8; ++ch) {
        float v[8];
#pragma unroll
        for (int q = 0; q < 8; ++q) {
            const int h = h0 + ch * 8 + q - W;
            if (CLAMP) {                    // branchless clamped load
                const int hc = min(max(h, 0), HH - 1);
                const float tv = img[(long)hc * WW + x];
                v[q] = (h == hc) ? tv : PAD;
            } else {                        // interior: plain load
                v[q] = img[(long)h * WW + x];
            }
        }
#pragma unroll
        for (int pp = 0; pp < 8; ++pp) {
#pragma unroll
            for (int q = 0; q < 8; q += 2) {            // paired -> v_max3
                const int d1 = ch * 8 + q - W - pp;     // compile-time
                const int d2 = d1 + 1;
                const bool ok1 = (d1 >= -W) && (d1 <= W);
                const bool ok2 = (d2 >= -W) && (d2 <= W);
                const float K1 = (float)(d1 * d1);
                const float K2 = (float)(d2 * d2);
                if (ok1 && ok2) {
                    const float c1 = IS_MAX ? fmaf(cw, -K1, v[q])
                                            : fmaf(cw,  K1, v[q]);
                    const float c2 = IS_MAX ? fmaf(cw, -K2, v[q + 1])
                                            : fmaf(cw,  K2, v[q + 1]);
                    acc[pp] = IS_MAX ? fmaxf(acc[pp], fmaxf(c1, c2))
                                     : fminf(acc[pp], fminf(c1, c2));
                } else if (ok1) {
                    const float c1 = IS_MAX ? fmaf(cw, -K1, v[q])
                                            : fmaf(cw,  K1, v[q]);
                    acc[pp] = IS_MAX ? fmaxf(acc[pp], c1) : fminf(acc[pp], c1);
                } else if (ok2) {
                    const float c2 = IS_MAX ? fmaf(cw, -K2, v[q + 1])
                                            : fmaf(cw,  K2, v[q + 1]);
                    acc[pp] = IS_MAX ? fmaxf(acc[pp], c2) : fminf(acc[pp], c2);
                }
            }
        }
    }
}

// ---- NT consecutive 8-row tiles per block, double-buffered LDS ----
template <int W, bool IS_MAX, int NT>
__device__ __forceinline__ void run_tiles(const float* __restrict__ ip,
                                          float* __restrict__ op,
                                          int y0, float c, float* lbuf)
{
    constexpr int LS = LdsStride<W>::v;
    const float cw = c * (4.0f / (float)(W * W));
    const float PAD = IS_MAX ? -1e30f : 1e30f;
    const int x = threadIdx.x;
    const int r = threadIdx.x >> 5, t = threadIdx.x & 31;

#pragma unroll 1
    for (int i = 0; i < NT; ++i) {
        float* buf = lbuf + (i & 1) * 8 * LS;           // dbuf: no trailing barrier
        const int h0 = (y0 + i) * 8;

        float vacc[8];
        if (h0 >= W && h0 + 8 + W <= HH)                // block-uniform branch
            vpass_core<W, IS_MAX, false>(ip, x, h0, cw, vacc);
        else
            vpass_core<W, IS_MAX, true >(ip, x, h0, cw, vacc);

#pragma unroll
        for (int q = 0; q < 8; ++q) buf[q * LS + W + x] = vacc[q];
        if (x < W) {
#pragma unroll
            for (int q = 0; q < 8; ++q) {
                buf[q * LS + x] = PAD;
                buf[q * LS + W + 256 + x] = PAD;
            }
        }
        __syncthreads();                                // the only barrier per tile

        float acc[8];
        hpass_lds<W, IS_MAX>(buf + r * LS + 8 * t, cw, acc);
        float* o = op + (long)(h0 + r) * WW + 8 * t;
        *(float4*)(o)     = make_float4(acc[0], acc[1], acc[2], acc[3]);
        *(float4*)(o + 4) = make_float4(acc[4], acc[5], acc[6], acc[7]);
    }
}

// ---- scale-clustered block decode (R10): rid = bid&255 picks the scale ----
__device__ __forceinline__ bool decode_block(int bid, int& k, int& z, int& y0)
{
    const int rid  = bid & 255;
    const int slot = bid >> 8;                          // 0..7
    int idx;
    if (rid < 128)      { k = 3; idx = rid * 8 + slot;
                          z = idx >> 5; y0 = idx & 31;        return true; }
    else if (rid < 192) { k = 2; idx = (rid - 128) * 8 + slot;
                          z = idx >> 4; y0 = (idx & 15) * 2;  return true; }
    else if (rid < 224) { k = 1; idx = (rid - 192) * 8 + slot;
                          z = idx >> 3; y0 = (idx & 7) * 4;   return true; }
    else if (rid < 240) { k = 0; idx = (rid - 224) * 8 + slot;
                          z = idx >> 2; y0 = (idx & 3) * 8;   return true; }
    return false;                                       // 16 idle residues
}

// ================= cooperative fused kernel: dil ; grid.sync ; ero ==========
__global__ __launch_bounds__(256, 8) void k_closing(const float* __restrict__ x,
                                                    float* __restrict__ ws,
                                                    float* __restrict__ out,
                                                    const float* __restrict__ cptr)
{
    __shared__ __align__(16) float lbuf[LBUF_FLOATS];
    int k, z, y0;
    const bool active = decode_block(blockIdx.x, k, z, y0);
    const float c = cptr[0];

    if (active) {                                       // phase DIL: x -> ws
        const float* ip = x + (long)z * HW;             // x shared across scales
        float* op = ws + (long)k * SLICE + (long)z * HW;
        switch (k) {
            case 0: run_tiles<4,  true, 8>(ip, op, y0, c, lbuf); break;
            case 1: run_tiles<8,  true, 4>(ip, op, y0, c, lbuf); break;
            case 2: run_tiles<16, true, 2>(ip, op, y0, c, lbuf); break;
            case 3: run_tiles<32, true, 1>(ip, op, y0, c, lbuf); break;
        }
    }
    cg::this_grid().sync();                             // idle blocks participate
    if (active) {                                       // phase ERO: ws -> out
        const float* ip = ws + (long)k * SLICE + (long)z * HW;
        float* op = out + (long)k * HW + (long)z * (long)NS * HW;
        switch (k) {
            case 0: run_tiles<4,  false, 8>(ip, op, y0, c, lbuf); break;
            case 1: run_tiles<8,  false, 4>(ip, op, y0, c, lbuf); break;
            case 2: run_tiles<16, false, 2>(ip, op, y0, c, lbuf); break;
            case 3: run_tiles<32, false, 1>(ip, op, y0, c, lbuf); break;
        }
    }
}

// ================= 2-dispatch fallback (R10-proven) =================
template <bool IS_MAX>
__global__ __launch_bounds__(256, 8) void k_vh(const float* __restrict__ in,
                                               float* __restrict__ out,
                                               const float* __restrict__ cptr,
                                               long in_ks, long in_zs,
                                               long out_ks, long out_zs,
                                               int kfix, int bpz, int zbase)
{
    __shared__ __align__(16) float lbuf[LBUF_FLOATS];
    const int bid = blockIdx.x;
    int k, y0, z;
    if (kfix < 0) {
        if (!decode_block(bid, k, z, y0)) return;
    } else {
        k = kfix;
        const int zi = bid / bpz;
        const int yi = bid - zi * bpz;
        z = zbase + zi;
        y0 = yi * (32 / bpz);
    }
    const float c = cptr[0];
    const float* ip = in + (long)k * in_ks + (long)z * in_zs;
    float* op = out + (long)k * out_ks + (long)z * out_zs;
    switch (k) {
        case 0: run_tiles<4,  IS_MAX, 8>(ip, op, y0, c, lbuf); break;
        case 1: run_tiles<8,  IS_MAX, 4>(ip, op, y0, c, lbuf); break;
        case 2: run_tiles<16, IS_MAX, 2>(ip, op, y0, c, lbuf); break;
        case 3: run_tiles<32, IS_MAX, 1>(ip, op, y0, c, lbuf); break;
    }
}

extern "C" void kernel_launch(void* const* d_in, const int* in_sizes, int n_in,
                              void* d_out, int out_size, void* d_ws, size_t ws_size,
                              hipStream_t stream)
{
    const float* x = (const float*)d_in[0];   // [4,8,256,256] fp32
    const float* c = (const float*)d_in[1];   // scalar se_coef
    float* out = (float*)d_out;               // [4,8,4,256,256] fp32
    float* ws  = (float*)d_ws;

    dim3 b(256);
    const size_t slice_b = (size_t)SLICE * sizeof(float);        // 8.4 MB
    if (ws_size >= (size_t)NS * slice_b) {
        // main path: ONE cooperative dispatch (dil ; grid.sync ; ero)
        void* args[] = {(void*)&x, (void*)&ws, (void*)&out, (void*)&c};
        hipError_t e = hipLaunchCooperativeKernel(
            reinterpret_cast<const void*>(&k_closing),
            dim3(2048), b, args, 0, stream);
        if (e == hipSuccess) return;
        // cooperative unsupported / capture refused -> proven 2-dispatch path
        dim3 g(2048);
        k_vh<true ><<<g, b, 0, stream>>>(x,  ws,  c, 0,     HW, SLICE, HW,
                                         -1, 0, 0);
        k_vh<false><<<g, b, 0, stream>>>(ws, out, c, SLICE, HW, HW, (long)NS * HW,
                                         -1, 0, 0);
    } else if (ws_size >= slice_b) {
        // per-scale fallback: one 8.4 MB ws slice reused across scales
        for (int k = 0; k < NS; ++k) {
            const int bpz = 4 << k;                 // blocks per z-slice
            dim3 g(bpz * BC);
            k_vh<true ><<<g, b, 0, stream>>>(x,  ws,  c, 0, HW, 0, HW,
                                             k, bpz, 0);
            k_vh<false><<<g, b, 0, stream>>>(ws, out, c, 0, HW, HW, (long)NS * HW,
                                             k, bpz, 0);
        }
    } else {
        // emergency fallback: one 256 KB ws tile per (scale, z) pair
        for (int k = 0; k < NS; ++k) {
            const int bpz = 4 << k;
            dim3 g(bpz);
            for (int z = 0; z < BC; ++z) {
                k_vh<true ><<<g, b, 0, stream>>>(x,  ws,  c, 0, HW, 0, 0,
                                                 k, bpz, z);
                k_vh<false><<<g, b, 0, stream>>>(ws, out, c, 0, 0, HW, (long)NS * HW,
                                                 k, bpz, z);
            }
        }
    }
}

// Round 9
// 121.228 us; speedup vs baseline: 3.5962x; 3.5962x over previous
//
#include <hip/hip_runtime.h>

// Multi-scale parabolic morphological closing, 2-dispatch fused pipeline.
// Algebra: dilations along different axes commute (max-plus), as do erosions:
//   closing = ev.eh.dv.dh = (eh.ev).(dh.dv)
//   K_dil: ws  = dh(dv(x))      (both max)
//   K_ero: out = eh(ev(ws))     (both min)
// weight(d) = c * (4/W^2) * d^2 — pow2 * small-int products are exact.
//
// R13 (from R12 post-mortem): R12's inter-block flag-spin hung the container
// (unbounded spin between non-cooperative blocks = hang risk under replay;
// lesson recorded). Revert to the R10-proven 2-dispatch structure (121.4us)
// and test ONE theory: per-tile load-dependency stalls. VGPR_Count=32 shows
// the compiler uses half its 64-reg budget -> loads are not pipelined ahead;
// each v-pass chunk serializes load8 -> wait -> compute (worst in K_ero:
// ws input is 33.5MB freshly written, mostly L2-miss ~900cyc). Fix:
// ONE-CHUNK-AHEAD register double buffer (vb[2][8], statically indexed under
// full unroll -> no scratch; R8's failure preloaded the WHOLE window) plus a
// one-ahead float4 LDS prefetch in the h-pass. Pure load reordering ->
// bit-exact (absmax stays 0.0). Predict VGPR ~40-48, k_vh 37 -> ~30us,
// total ~108-112; if ~121, latency theory falsified (-> barrier-burst floor).

#define HH 256
#define WW 256
#define BC 32
#define NS 4
#define HW (HH * WW)
#define SLICE ((long)BC * HW)

// LDS row stride per scale: 2W + 256 + 4 (multiple of 4 floats -> 16B rows)
template <int W> struct LdsStride { static constexpr int v = 2 * W + 256 + 4; };
#define LBUF_FLOATS (2 * 8 * 292)

// ---- horizontal pass over one padded LDS row; thread computes 8 outputs ----
// lw = row base + 8*t (16B-aligned); element o in [0, 2W+8) maps to d = o-W-pp
template <int W, bool IS_MAX>
__device__ __forceinline__ void hpass_lds(const float* __restrict__ lw, float cw,
                                          float acc[8])
{
    const float PAD = IS_MAX ? -1e30f : 1e30f;
    constexpr int NU = (8 + 2 * W) / 4;
#pragma unroll
    for (int pp = 0; pp < 8; ++pp) acc[pp] = PAD;

    const float4* lw4 = (const float4*)lw;
    float4 cur = lw4[0];                                // prefetch depth 1
#pragma unroll
    for (int u = 0; u < NU; ++u) {
        float4 nxt;
        if (u + 1 < NU) nxt = lw4[u + 1];               // issue next LDS read
        const float vs[4] = {cur.x, cur.y, cur.z, cur.w};
#pragma unroll
        for (int pp = 0; pp < 8; ++pp) {
#pragma unroll
            for (int e = 0; e < 4; e += 2) {            // paired -> v_max3
                const int d1 = 4 * u + e - W - pp;      // compile-time
                const int d2 = d1 + 1;
                const bool ok1 = (d1 >= -W) && (d1 <= W);
                const bool ok2 = (d2 >= -W) && (d2 <= W);
                const float K1 = (float)(d1 * d1);
                const float K2 = (float)(d2 * d2);
                if (ok1 && ok2) {
                    const float c1 = IS_MAX ? fmaf(cw, -K1, vs[e])
                                            : fmaf(cw,  K1, vs[e]);
                    const float c2 = IS_MAX ? fmaf(cw, -K2, vs[e + 1])
                                            : fmaf(cw,  K2, vs[e + 1]);
                    acc[pp] = IS_MAX ? fmaxf(acc[pp], fmaxf(c1, c2))
                                     : fminf(acc[pp], fminf(c1, c2));
                } else if (ok1) {
                    const float c1 = IS_MAX ? fmaf(cw, -K1, vs[e])
                                            : fmaf(cw,  K1, vs[e]);
                    acc[pp] = IS_MAX ? fmaxf(acc[pp], c1) : fminf(acc[pp], c1);
                } else if (ok2) {
                    const float c2 = IS_MAX ? fmaf(cw, -K2, vs[e + 1])
                                            : fmaf(cw,  K2, vs[e + 1]);
                    acc[pp] = IS_MAX ? fmaxf(acc[pp], c2) : fminf(acc[pp], c2);
                }
            }
        }
        cur = nxt;
    }
}

// ---- vertical pass; thread = one column, 8 consecutive output rows ----
// CLAMP=false: caller guarantees rows [h0-W, h0+7+W] are all in-bounds.
// One-chunk-ahead register double buffer (vb indexed by compile-time ch&1).
template <int W, bool IS_MAX, bool CLAMP>
__device__ __forceinline__ void vpass_core(const float* __restrict__ img, int x,
                                           int h0, float cw, float acc[8])
{
    const float PAD = IS_MAX ? -1e30f : 1e30f;
    constexpr int TOT = 8 + 2 * W;
    constexpr int NCH = TOT / 8;
#pragma unroll
    for (int pp = 0; pp < 8; ++pp) acc[pp] = PAD;

    float vb[2][8];
    auto loadch = [&](int ch, float* v) {
#pragma unroll
        for (int q = 0; q < 8; ++q) {
            const int h = h0 + ch * 8 + q - W;
            if (CLAMP) {                    // branchless clamped load
                const int hc = min(max(h, 0), HH - 1);
                const float tv = img[(long)hc * WW + x];
                v[q] = (h == hc) ? tv : PAD;
            } else {                        // interior: plain load
                v[q] = img[(long)h * WW + x];
            }
        }
    };

    loadch(0, vb[0]);
#pragma unroll
    for (int ch = 0; ch < NCH; ++ch) {
        if (ch + 1 < NCH) loadch(ch + 1, vb[(ch + 1) & 1]);  // prefetch next
        const float* v = vb[ch & 1];                          // static index
#pragma unroll
        for (int pp = 0; pp < 8; ++pp) {
#pragma unroll
            for (int q = 0; q < 8; q += 2) {            // paired -> v_max3
                const int d1 = ch * 8 + q - W - pp;     // compile-time
                const int d2 = d1 + 1;
                const bool ok1 = (d1 >= -W) && (d1 <= W);
                const bool ok2 = (d2 >= -W) && (d2 <= W);
                const float K1 = (float)(d1 * d1);
                const float K2 = (float)(d2 * d2);
                if (ok1 && ok2) {
                    const float c1 = IS_MAX ? fmaf(cw, -K1, v[q])
                                            : fmaf(cw,  K1, v[q]);
                    const float c2 = IS_MAX ? fmaf(cw, -K2, v[q + 1])
                                            : fmaf(cw,  K2, v[q + 1]);
                    acc[pp] = IS_MAX ? fmaxf(acc[pp], fmaxf(c1, c2))
                                     : fminf(acc[pp], fminf(c1, c2));
                } else if (ok1) {
                    const float c1 = IS_MAX ? fmaf(cw, -K1, v[q])
                                            : fmaf(cw,  K1, v[q]);
                    acc[pp] = IS_MAX ? fmaxf(acc[pp], c1) : fminf(acc[pp], c1);
                } else if (ok2) {
                    const float c2 = IS_MAX ? fmaf(cw, -K2, v[q + 1])
                                            : fmaf(cw,  K2, v[q + 1]);
                    acc[pp] = IS_MAX ? fmaxf(acc[pp], c2) : fminf(acc[pp], c2);
                }
            }
        }
    }
}

// ---- NT consecutive 8-row tiles per block, double-buffered LDS ----
template <int W, bool IS_MAX, int NT>
__device__ __forceinline__ void run_tiles(const float* __restrict__ ip,
                                          float* __restrict__ op,
                                          int y0, float c, float* lbuf)
{
    constexpr int LS = LdsStride<W>::v;
    const float cw = c * (4.0f / (float)(W * W));
    const float PAD = IS_MAX ? -1e30f : 1e30f;
    const int x = threadIdx.x;
    const int r = threadIdx.x >> 5, t = threadIdx.x & 31;

#pragma unroll 1
    for (int i = 0; i < NT; ++i) {
        float* buf = lbuf + (i & 1) * 8 * LS;           // dbuf: no trailing barrier
        const int h0 = (y0 + i) * 8;

        float vacc[8];
        if (h0 >= W && h0 + 8 + W <= HH)                // block-uniform branch
            vpass_core<W, IS_MAX, false>(ip, x, h0, cw, vacc);
        else
            vpass_core<W, IS_MAX, true >(ip, x, h0, cw, vacc);

#pragma unroll
        for (int q = 0; q < 8; ++q) buf[q * LS + W + x] = vacc[q];
        if (x < W) {
#pragma unroll
            for (int q = 0; q < 8; ++q) {
                buf[q * LS + x] = PAD;
                buf[q * LS + W + 256 + x] = PAD;
            }
        }
        __syncthreads();                                // the only barrier per tile

        float acc[8];
        hpass_lds<W, IS_MAX>(buf + r * LS + 8 * t, cw, acc);
        float* o = op + (long)(h0 + r) * WW + 8 * t;
        *(float4*)(o)     = make_float4(acc[0], acc[1], acc[2], acc[3]);
        *(float4*)(o + 4) = make_float4(acc[4], acc[5], acc[6], acc[7]);
    }
}

// ---- scale-clustered block decode (R10): rid = bid&255 picks the scale ----
__device__ __forceinline__ bool decode_block(int bid, int& k, int& z, int& y0)
{
    const int rid  = bid & 255;
    const int slot = bid >> 8;                          // 0..7
    int idx;
    if (rid < 128)      { k = 3; idx = rid * 8 + slot;
                          z = idx >> 5; y0 = idx & 31;        return true; }
    else if (rid < 192) { k = 2; idx = (rid - 128) * 8 + slot;
                          z = idx >> 4; y0 = (idx & 15) * 2;  return true; }
    else if (rid < 224) { k = 1; idx = (rid - 192) * 8 + slot;
                          z = idx >> 3; y0 = (idx & 7) * 4;   return true; }
    else if (rid < 240) { k = 0; idx = (rid - 224) * 8 + slot;
                          z = idx >> 2; y0 = (idx & 3) * 8;   return true; }
    return false;                                       // 16 idle residues
}

// ================= the 2-dispatch kernels =================
template <bool IS_MAX>
__global__ __launch_bounds__(256, 8) void k_vh(const float* __restrict__ in,
                                               float* __restrict__ out,
                                               const float* __restrict__ cptr,
                                               long in_ks, long in_zs,
                                               long out_ks, long out_zs,
                                               int kfix, int bpz, int zbase)
{
    __shared__ __align__(16) float lbuf[LBUF_FLOATS];
    const int bid = blockIdx.x;
    int k, y0, z;
    if (kfix < 0) {
        if (!decode_block(bid, k, z, y0)) return;
    } else {
        k = kfix;
        const int zi = bid / bpz;
        const int yi = bid - zi * bpz;
        z = zbase + zi;
        y0 = yi * (32 / bpz);
    }
    const float c = cptr[0];
    const float* ip = in + (long)k * in_ks + (long)z * in_zs;
    float* op = out + (long)k * out_ks + (long)z * out_zs;
    switch (k) {
        case 0: run_tiles<4,  IS_MAX, 8>(ip, op, y0, c, lbuf); break;
        case 1: run_tiles<8,  IS_MAX, 4>(ip, op, y0, c, lbuf); break;
        case 2: run_tiles<16, IS_MAX, 2>(ip, op, y0, c, lbuf); break;
        case 3: run_tiles<32, IS_MAX, 1>(ip, op, y0, c, lbuf); break;
    }
}

extern "C" void kernel_launch(void* const* d_in, const int* in_sizes, int n_in,
                              void* d_out, int out_size, void* d_ws, size_t ws_size,
                              hipStream_t stream)
{
    const float* x = (const float*)d_in[0];   // [4,8,256,256] fp32
    const float* c = (const float*)d_in[1];   // scalar se_coef
    float* out = (float*)d_out;               // [4,8,4,256,256] fp32
    float* ws  = (float*)d_ws;

    dim3 b(256);
    const size_t slice_b = (size_t)SLICE * sizeof(float);        // 8.4 MB
    if (ws_size >= (size_t)NS * slice_b) {
        // main path: 2 dispatches, scale-clustered 2048-block grid
        dim3 g(2048);
        // K_dil: ws[k,z] = dh(dv(x[z]))   (x shared across scales: in_ks = 0)
        k_vh<true ><<<g, b, 0, stream>>>(x,  ws,  c, 0,     HW, SLICE, HW,
                                         -1, 0, 0);
        // K_ero: out[z,k] = eh(ev(ws[k,z]))
        k_vh<false><<<g, b, 0, stream>>>(ws, out, c, SLICE, HW, HW, (long)NS * HW,
                                         -1, 0, 0);
    } else if (ws_size >= slice_b) {
        // per-scale fallback: one 8.4 MB ws slice reused across scales
        for (int k = 0; k < NS; ++k) {
            const int bpz = 4 << k;                 // blocks per z-slice
            dim3 g(bpz * BC);
            k_vh<true ><<<g, b, 0, stream>>>(x,  ws,  c, 0, HW, 0, HW,
                                             k, bpz, 0);
            k_vh<false><<<g, b, 0, stream>>>(ws, out, c, 0, HW, HW, (long)NS * HW,
                                             k, bpz, 0);
        }
    } else {
        // emergency fallback: one 256 KB ws tile per (scale, z) pair
        for (int k = 0; k < NS; ++k) {
            const int bpz = 4 << k;
            dim3 g(bpz);
            for (int z = 0; z < BC; ++z) {
                k_vh<true ><<<g, b, 0, stream>>>(x,  ws,  c, 0, HW, 0, 0,
                                                 k, bpz, z);
                k_vh<false><<<g, b, 0, stream>>>(ws, out, c, 0, 0, HW, (long)NS * HW,
                                                 k, bpz, z);
            }
        }
    }
}

// Round 10
// 119.564 us; speedup vs baseline: 3.6463x; 1.0139x over previous
//
#include <hip/hip_runtime.h>

// Multi-scale parabolic morphological closing, 2-dispatch fused pipeline.
// Algebra: dilations along different axes commute (max-plus), as do erosions:
//   closing = ev.eh.dv.dh = (eh.ev).(dh.dv)
//   K_dil: ws  = dh(dv(x))      (both max)
//   K_ero: out = eh(ev(ws))     (both min)
// weight(d) = c * (4/W^2) * d^2 — pow2 * small-int products are exact.
//
// R14 — FINAL: exact revert to the session's empirical minimum (R7, 119.8us).
// R8-R13 tested and falsified, all neutral within +-1.5% noise:
//   pairing->v_max3 (clang already fuses), LDS dbuf/1-barrier, full preload
//   (regressed: spill), scale-clustered I$ mapping, reg double-buffer
//   prefetch. Structural attacks on the ~13us/dispatch ramp-drain term
//   (backed by 62% vs 93% occupancy, R11): grid.sync = +300us (R11),
//   flag-spin = hang (R12), redundant-dil = +31% work / 2x tail (computed).
// Structural floor: 47.5 harness ws-fill (HBM-bound, immovable)
//   + 2 x (17 VALU-busy + ~6 mem + ~13 dispatch-shape) ~= 120us.
// Equal-work blocks NT={8,4,2,1} for W={4,8,16,32}, 1920-block grid, single
// residency round; interior/boundary clamp split; float4 LDS h-pass;
// __launch_bounds__(256,8). Math identical to reference -> absmax 0.0.

#define HH 256
#define WW 256
#define BC 32
#define NS 4
#define HW (HH * WW)
#define SLICE ((long)BC * HW)
#define LSTR 324   // LDS row stride in floats: 2*32+256+4 (16B-aligned rows)

// ---- horizontal pass over one padded LDS row; thread computes 8 outputs ----
// lw = row base + 8*t (16B-aligned); element o in [0, 2W+8) maps to d = o-W-pp
template <int W, bool IS_MAX>
__device__ __forceinline__ void hpass_lds(const float* __restrict__ lw, float cw,
                                          float acc[8])
{
    const float PAD = IS_MAX ? -1e30f : 1e30f;
#pragma unroll
    for (int pp = 0; pp < 8; ++pp) acc[pp] = PAD;
#pragma unroll
    for (int u = 0; u < (8 + 2 * W) / 4; ++u) {
        const float4 vv = *(const float4*)(lw + 4 * u);
        const float vs[4] = {vv.x, vv.y, vv.z, vv.w};
#pragma unroll
        for (int pp = 0; pp < 8; ++pp) {
#pragma unroll
            for (int e = 0; e < 4; ++e) {
                const int d = 4 * u + e - W - pp;          // compile-time
                if (d >= -W && d <= W) {
                    const float K = (float)(d * d);
                    const float cand = IS_MAX ? fmaf(cw, -K, vs[e])
                                              : fmaf(cw,  K, vs[e]);
                    acc[pp] = IS_MAX ? fmaxf(acc[pp], cand) : fminf(acc[pp], cand);
                }
            }
        }
    }
}

// ---- vertical pass; thread = one column, 8 consecutive output rows ----
// CLAMP=false: caller guarantees rows [h0-W, h0+7+W] are all in-bounds.
template <int W, bool IS_MAX, bool CLAMP>
__device__ __forceinline__ void vpass_core(const float* __restrict__ img, int x,
                                           int h0, float cw, float acc[8])
{
    const float PAD = IS_MAX ? -1e30f : 1e30f;
#pragma unroll
    for (int pp = 0; pp < 8; ++pp) acc[pp] = PAD;
#pragma unroll
    for (int ch = 0; ch < (8 + 2 * W) / 8; ++ch) {
        float v[8];
#pragma unroll
        for (int q = 0; q < 8; ++q) {
            const int h = h0 + ch * 8 + q - W;
            if (CLAMP) {                    // branchless clamped load
                const int hc = min(max(h, 0), HH - 1);
                const float tv = img[(long)hc * WW + x];
                v[q] = (h == hc) ? tv : PAD;
            } else {                        // interior: plain load
                v[q] = img[(long)h * WW + x];
            }
        }
#pragma unroll
        for (int pp = 0; pp < 8; ++pp) {
#pragma unroll
            for (int q = 0; q < 8; ++q) {
                const int d = ch * 8 + q - W - pp;          // compile-time
                if (d >= -W && d <= W) {
                    const float K = (float)(d * d);
                    const float cand = IS_MAX ? fmaf(cw, -K, v[q])
                                              : fmaf(cw,  K, v[q]);
                    acc[pp] = IS_MAX ? fmaxf(acc[pp], cand) : fminf(acc[pp], cand);
                }
            }
        }
    }
}

// ---- one fused v-then-h tile: 8 rows x 256 cols ----
template <int W, bool IS_MAX>
__device__ __forceinline__ void vh_tile(const float* __restrict__ img,
                                        float* __restrict__ op_base,
                                        int h0, float cw, float* lbuf)
{
    const int x = threadIdx.x;
    const float PAD = IS_MAX ? -1e30f : 1e30f;

    // phase 1: vertical pass for 8 rows (thread-per-column)
    float vacc[8];
    if (h0 >= W && h0 + 8 + W <= HH)        // block-uniform branch
        vpass_core<W, IS_MAX, false>(img, x, h0, cw, vacc);
    else
        vpass_core<W, IS_MAX, true >(img, x, h0, cw, vacc);

    // stash as padded LDS rows for the horizontal pass
#pragma unroll
    for (int q = 0; q < 8; ++q) lbuf[q * LSTR + W + x] = vacc[q];
    if (x < W) {
#pragma unroll
        for (int q = 0; q < 8; ++q) {
            lbuf[q * LSTR + x] = PAD;
            lbuf[q * LSTR + W + 256 + x] = PAD;
        }
    }
    __syncthreads();

    // phase 2: horizontal pass on the 8-row tile
    const int r = threadIdx.x >> 5, t = threadIdx.x & 31;
    float acc[8];
    hpass_lds<W, IS_MAX>(lbuf + r * LSTR + 8 * t, cw, acc);
    float* op = op_base + (long)(h0 + r) * WW + 8 * t;
    *(float4*)(op)     = make_float4(acc[0], acc[1], acc[2], acc[3]);
    *(float4*)(op + 4) = make_float4(acc[4], acc[5], acc[6], acc[7]);

    __syncthreads();                        // lbuf reused by next tile
}

// ---- NT consecutive tiles per block (equal-work scheduling) ----
template <int W, bool IS_MAX, int NT>
__device__ __forceinline__ void run_tiles(const float* __restrict__ ip,
                                          float* __restrict__ op,
                                          int y0, float c, float* lbuf)
{
    const float cw = c * (4.0f / (float)(W * W));
#pragma unroll 1
    for (int i = 0; i < NT; ++i)
        vh_tile<W, IS_MAX>(ip, op, (y0 + i) * 8, cw, lbuf);
}

// ---- kernel ----
// kfix < 0 : full decode, 60 equal-work blocks per z-slice:
//   r<32 -> k=3 (1 tile); r<48 -> k=2 (2 tiles); r<56 -> k=1 (4); else k=0 (8)
// kfix >= 0: single-scale mode, bpz blocks per z, z = zbase + bid/bpz.
template <bool IS_MAX>
__global__ __launch_bounds__(256, 8) void k_vh(const float* __restrict__ in,
                                               float* __restrict__ out,
                                               const float* __restrict__ cptr,
                                               long in_ks, long in_zs,
                                               long out_ks, long out_zs,
                                               int kfix, int bpz, int zbase)
{
    __shared__ float lbuf[8 * LSTR];
    const int bid = blockIdx.x;
    int k, y0, z;
    if (kfix < 0) {
        z = bid / 60;
        const int r = bid - z * 60;
        if (r < 32)      { k = 3; y0 = r; }
        else if (r < 48) { k = 2; y0 = (r - 32) * 2; }
        else if (r < 56) { k = 1; y0 = (r - 48) * 4; }
        else             { k = 0; y0 = (r - 56) * 8; }
    } else {
        k = kfix;
        const int zi = bid / bpz;
        const int yi = bid - zi * bpz;
        z = zbase + zi;
        y0 = yi * (32 / bpz);
    }
    const float c = cptr[0];
    const float* ip = in + (long)k * in_ks + (long)z * in_zs;
    float* op = out + (long)k * out_ks + (long)z * out_zs;
    switch (k) {
        case 0: run_tiles<4,  IS_MAX, 8>(ip, op, y0, c, lbuf); break;
        case 1: run_tiles<8,  IS_MAX, 4>(ip, op, y0, c, lbuf); break;
        case 2: run_tiles<16, IS_MAX, 2>(ip, op, y0, c, lbuf); break;
        case 3: run_tiles<32, IS_MAX, 1>(ip, op, y0, c, lbuf); break;
    }
}

extern "C" void kernel_launch(void* const* d_in, const int* in_sizes, int n_in,
                              void* d_out, int out_size, void* d_ws, size_t ws_size,
                              hipStream_t stream)
{
    const float* x = (const float*)d_in[0];   // [4,8,256,256] fp32
    const float* c = (const float*)d_in[1];   // scalar se_coef
    float* out = (float*)d_out;               // [4,8,4,256,256] fp32
    float* ws  = (float*)d_ws;

    dim3 b(256);
    const size_t slice_b = (size_t)SLICE * sizeof(float);        // 8.4 MB
    if (ws_size >= (size_t)NS * slice_b) {
        // main path: 2 dispatches, 60 equal-work blocks per z => 1920 blocks
        dim3 g(60 * BC);
        // K_dil: ws[k,z] = dh(dv(x[z]))   (x shared across scales: in_ks = 0)
        k_vh<true ><<<g, b, 0, stream>>>(x,  ws,  c, 0,     HW, SLICE, HW,
                                         -1, 0, 0);
        // K_ero: out[z,k] = eh(ev(ws[k,z]))
        k_vh<false><<<g, b, 0, stream>>>(ws, out, c, SLICE, HW, HW, (long)NS * HW,
                                         -1, 0, 0);
    } else if (ws_size >= slice_b) {
        // per-scale fallback: one 8.4 MB ws slice reused across scales
        for (int k = 0; k < NS; ++k) {
            const int bpz = 4 << k;                 // blocks per z-slice
            dim3 g(bpz * BC);
            k_vh<true ><<<g, b, 0, stream>>>(x,  ws,  c, 0, HW, 0, HW,
                                             k, bpz, 0);
            k_vh<false><<<g, b, 0, stream>>>(ws, out, c, 0, HW, HW, (long)NS * HW,
                                             k, bpz, 0);
        }
    } else {
        // emergency fallback: one 256 KB ws tile per (scale, z) pair
        for (int k = 0; k < NS; ++k) {
            const int bpz = 4 << k;
            dim3 g(bpz);
            for (int z = 0; z < BC; ++z) {
                k_vh<true ><<<g, b, 0, stream>>>(x,  ws,  c, 0, HW, 0, 0,
                                                 k, bpz, z);
                k_vh<false><<<g, b, 0, stream>>>(ws, out, c, 0, 0, HW, (long)NS * HW,
                                                 k, bpz, z);
            }
        }
    }
}